// Round 1
// baseline (343.557 us; speedup 1.0000x reference)
//
#include <hip/hip_runtime.h>
#include <math.h>

// Problem constants: B=256, LMAX=512, NCOND=300, NHID=600
#define BB     256
#define LMAX   512
#define NCOND  300
#define NHID   600
#define NSEG   8          // 8 segments of 64 tokens; block = one segment chunk
#define CHUNK  64
#define KPAD   320        // K padded to 10 chunks of 32 (k>=300 zero in W1T)
#define KLDS   328        // LDS row stride (elems): 656 B, 16B-aligned, 2-way bank alias = free
#define NCOLP  640        // hidden padded to 40 tiles of 16
#define NKC    10         // KPAD/32

typedef short s16x8 __attribute__((ext_vector_type(8)));  // MFMA A/B frag (8 bf16)
typedef float f32x4 __attribute__((ext_vector_type(4)));  // MFMA accumulator

// fp32 -> bf16 round-to-nearest-even
__device__ inline unsigned short f2bf(float f) {
    unsigned int x = __float_as_uint(f);
    x += 0x7fffu + ((x >> 16) & 1u);
    return (unsigned short)(x >> 16);
}

// ---------------------------------------------------------------------------
// k0: build W1T bf16 in FRAGMENT-MAJOR layout:
//   w1t[((ntile*NKC + kc)*64 + lane)*8 + j] = W1[kc*32+(lane>>4)*8+j][ntile*16+(lane&15)]
// -> a wave's B-frag load is one contiguous 1 KB global_load_dwordx4.
// ---------------------------------------------------------------------------
__global__ __launch_bounds__(256) void k0_w1t(const float* __restrict__ W1,
                                              unsigned short* __restrict__ w1t)
{
    const int t     = blockIdx.x * 256 + threadIdx.x;  // 0..25599
    const int lane  = t & 63;
    const int g     = t >> 6;                          // ntile*NKC + kc
    const int ntile = g / NKC;
    const int kc    = g - ntile * NKC;
    const int n     = ntile * 16 + (lane & 15);
    const int kbase = kc * 32 + (lane >> 4) * 8;
    union { unsigned short us[8]; s16x8 v8; } u;
#pragma unroll
    for (int j = 0; j < 8; ++j) {
        const int k = kbase + j;
        const float w = (n < NHID && k < NCOND) ? W1[(size_t)k * NHID + n] : 0.f;
        u.us[j] = f2bf(w);
    }
    *(s16x8*)(w1t + (size_t)t * 8) = u.v8;
}

// ---------------------------------------------------------------------------
// k1 v2: grid (BB, NSEG, 2). Block = ONE 64-row chunk of one batch, one
//     col-half. Changes vs v1 (latency-exposure fixes, register-neutral):
//   (a) BRANCHLESS row staging: rows >= valid are loaded anyway (real floats,
//       outputs discarded by the epilogue row mask) -> uniform control flow.
//   (b) Manual depth-5 rolling load pipeline: 5 iterations' float4 loads are
//       kept in flight (40 VGPRs) so staging pays ~2 HBM round trips, not ~10.
//       Fully unrolled with literal slot indices (no dynamic-index scratch).
//   (c) b1 bias slice staged into LDS during staging (its 2 loads issued
//       FIRST so their waitcnt doesn't drain the staging queue); epilogue
//       reads LDS instead of 5 global loads.
// ---------------------------------------------------------------------------
__global__ __launch_bounds__(256, 3) void k1_mfma_pool(
    const float* __restrict__ ctx, const int* __restrict__ lengths,
    const unsigned short* __restrict__ w1t, const float* __restrict__ b1,
    float* __restrict__ partial)
{
    const int b  = blockIdx.x;
    const int s  = blockIdx.y;
    const int ch = blockIdx.z;

    int count = lengths[b]; if (count < 1) count = 1;   // reference clamps lens >= 1
    const int l0 = s * CHUNK;
    if (l0 >= count) return;                            // empty segment: no work, no write
    const int valid = min(count - l0, CHUNK);

    const int tid  = threadIdx.x;
    const int lane = tid & 63;
    const int wv   = tid >> 6;
    const int ln15 = lane & 15;
    const int kg   = lane >> 4;

    __shared__ __align__(16) unsigned short atile[CHUNK * KLDS];   // 41,984 B
    __shared__ float b1s[320];                                      // +1,280 B

    // ---- b1 loads issued first (oldest in the vm queue)
    float bv0, bv1;
    {
        const int c0 = ch * 320 + tid;
        bv0 = (c0 < NHID) ? b1[c0] : 0.f;
        const int c1 = ch * 320 + 256 + tid;
        bv1 = (tid < 64 && c1 < NHID) ? b1[c1] : 0.f;
    }

    // ---- stage 64 x KPAD bf16, branchless over rows; k >= 300 zero-filled.
    //      Rows >= valid contain real ctx data (or neighboring tokens) and are
    //      masked out in the epilogue -> valid outputs bit-identical.
    const float4 z4 = make_float4(0.f, 0.f, 0.f, 0.f);
    float4 sa[5], sb[5];

#define STG_ISSUE(p, sl) { \
    const int i_  = (p) * 256 + tid; \
    const int r_  = i_ / 40; \
    const int c8_ = i_ - r_ * 40; \
    const float* src_ = ctx + ((size_t)b * LMAX + l0 + r_) * NCOND + c8_ * 8; \
    sa[sl] = (c8_ < 38) ? *(const float4*)src_ : z4; \
    sb[sl] = (c8_ < 37) ? *(const float4*)(src_ + 4) : z4; }

#define STG_COMMIT(p, sl) { \
    const int i_  = (p) * 256 + tid; \
    const int r_  = i_ / 40; \
    const int c8_ = i_ - r_ * 40; \
    union { unsigned short us[8]; s16x8 v8; } u_; \
    u_.us[0] = f2bf(sa[sl].x); u_.us[1] = f2bf(sa[sl].y); \
    u_.us[2] = f2bf(sa[sl].z); u_.us[3] = f2bf(sa[sl].w); \
    u_.us[4] = f2bf(sb[sl].x); u_.us[5] = f2bf(sb[sl].y); \
    u_.us[6] = f2bf(sb[sl].z); u_.us[7] = f2bf(sb[sl].w); \
    *(s16x8*)(atile + r_ * KLDS + c8_ * 8) = u_.v8; }

    STG_ISSUE(0, 0)
    STG_ISSUE(1, 1)
    STG_ISSUE(2, 2)
    STG_ISSUE(3, 3)
    STG_ISSUE(4, 4)

    // b1 -> LDS (waits only on the two oldest loads; staging stays in flight)
    b1s[tid] = bv0;
    if (tid < 64) b1s[256 + tid] = bv1;

    STG_COMMIT(0, 0) STG_ISSUE(5, 0)
    STG_COMMIT(1, 1) STG_ISSUE(6, 1)
    STG_COMMIT(2, 2) STG_ISSUE(7, 2)
    STG_COMMIT(3, 3) STG_ISSUE(8, 3)
    STG_COMMIT(4, 4) STG_ISSUE(9, 4)
    STG_COMMIT(5, 0)
    STG_COMMIT(6, 1)
    STG_COMMIT(7, 2)
    STG_COMMIT(8, 3)
    STG_COMMIT(9, 4)

#undef STG_ISSUE
#undef STG_COMMIT

    __syncthreads();

    // ---- MFMA: wave wv owns cols [ch*320 + wv*80, +80) = 5 n-tiles x 4 m-tiles
    const int ntile0 = ch * 20 + wv * 5;
    const unsigned short* bbase = w1t + ((size_t)ntile0 * NKC * 64 + lane) * 8;
    const unsigned short* arow  = atile + ln15 * KLDS + kg * 8;

    f32x4 acc[5][4];
#pragma unroll
    for (int nt = 0; nt < 5; ++nt)
#pragma unroll
        for (int mt = 0; mt < 4; ++mt) acc[nt][mt] = (f32x4){0.f, 0.f, 0.f, 0.f};

    s16x8 bf[2][5];
#pragma unroll
    for (int nt = 0; nt < 5; ++nt) bf[0][nt] = *(const s16x8*)(bbase + nt * 5120);

#pragma unroll
    for (int kc = 0; kc < NKC; ++kc) {
        const int cur = kc & 1, nxt = cur ^ 1;
        if (kc < NKC - 1) {
#pragma unroll
            for (int nt = 0; nt < 5; ++nt)
                bf[nxt][nt] = *(const s16x8*)(bbase + nt * 5120 + (kc + 1) * 512);
        }
        s16x8 af[4];
#pragma unroll
        for (int mt = 0; mt < 4; ++mt)
            af[mt] = *(const s16x8*)(arow + mt * 16 * KLDS + kc * 32);
#pragma unroll
        for (int nt = 0; nt < 5; ++nt)
#pragma unroll
            for (int mt = 0; mt < 4; ++mt)
                acc[nt][mt] = __builtin_amdgcn_mfma_f32_16x16x32_bf16(
                    af[mt], bf[cur][nt], acc[nt][mt], 0, 0, 0);
    }

    // ---- epilogue: bias (LDS) + ReLU, mask rows >= valid, reduce k-groups, write
#pragma unroll
    for (int nt = 0; nt < 5; ++nt) {
        const int cloc = wv * 80 + nt * 16 + ln15;     // 0..319 within col-half
        const int colg = ch * 320 + cloc;
        const float b1c = b1s[cloc];
        float ssum = 0.f;
#pragma unroll
        for (int mt = 0; mt < 4; ++mt) {
            const int rbase = mt * 16 + kg * 4;
#pragma unroll
            for (int r = 0; r < 4; ++r) {
                const float h = fmaxf(acc[nt][mt][r] + b1c, 0.f);
                if (rbase + r < valid) ssum += h;
            }
        }
        ssum += __shfl_xor(ssum, 16, 64);
        ssum += __shfl_xor(ssum, 32, 64);
        if (kg == 0 && colg < NHID)
            partial[((size_t)s * BB + b) * NHID + colg] = ssum;
    }
}

// ---------------------------------------------------------------------------
// k2: 2 batches per block (same-n lanes share Wa loads). Reduce partials over
//     sp < ceil(len/64) (others unwritten/poisoned -> skipped), /len, then
//     gate = sigmoid(pooled@Wa + ba); out = gate * x.
// NOTE: NHID/4 = 150 float4s = 37*4 + 2 -> 4-wide main loop to h4<148, then
//       a 2-float4 tail. (Round 4 bug: stepping 4 to 150 overran pl AND Wa.)
// ---------------------------------------------------------------------------
__global__ __launch_bounds__(640) void k2_gate(
    const float* __restrict__ x, const int* __restrict__ lengths,
    const float* __restrict__ partial, const float* __restrict__ Wa,
    const float* __restrict__ ba, float* __restrict__ out)
{
    const int b0  = blockIdx.x * 2;
    const int tid = threadIdx.x;

    __shared__ float pl[2][NHID];

    if (tid < NHID) {
#pragma unroll
        for (int bb = 0; bb < 2; ++bb) {
            int count = lengths[b0 + bb]; if (count < 1) count = 1;
            const int nch = (count + CHUNK - 1) >> 6;
            float ssum = 0.f;
            for (int sp = 0; sp < nch; ++sp)
                ssum += partial[((size_t)sp * BB + (b0 + bb)) * NHID + tid];
            pl[bb][tid] = ssum / (float)count;
        }
    }
    __syncthreads();

    if (tid < 2 * NCOND) {
        const int bb = tid / NCOND;        // 0 or 1
        const int n  = tid - bb * NCOND;   // lanes 0..299 and 300..599 share Wa addrs
        const int b  = b0 + bb;
        float a0 = ba[n], a1 = 0.f, a2 = 0.f, a3 = 0.f;
        const float4* p4 = (const float4*)pl[bb];
        for (int h4 = 0; h4 < 148; h4 += 4) {   // h = 0..591
            const float4 pv0 = p4[h4];
            const float4 pv1 = p4[h4 + 1];
            const float4 pv2 = p4[h4 + 2];
            const float4 pv3 = p4[h4 + 3];
            const int hb = h4 * 4;
            a0 = fmaf(pv0.x, Wa[(size_t)(hb +  0) * NCOND + n], a0);
            a0 = fmaf(pv0.y, Wa[(size_t)(hb +  1) * NCOND + n], a0);
            a0 = fmaf(pv0.z, Wa[(size_t)(hb +  2) * NCOND + n], a0);
            a0 = fmaf(pv0.w, Wa[(size_t)(hb +  3) * NCOND + n], a0);
            a1 = fmaf(pv1.x, Wa[(size_t)(hb +  4) * NCOND + n], a1);
            a1 = fmaf(pv1.y, Wa[(size_t)(hb +  5) * NCOND + n], a1);
            a1 = fmaf(pv1.z, Wa[(size_t)(hb +  6) * NCOND + n], a1);
            a1 = fmaf(pv1.w, Wa[(size_t)(hb +  7) * NCOND + n], a1);
            a2 = fmaf(pv2.x, Wa[(size_t)(hb +  8) * NCOND + n], a2);
            a2 = fmaf(pv2.y, Wa[(size_t)(hb +  9) * NCOND + n], a2);
            a2 = fmaf(pv2.z, Wa[(size_t)(hb + 10) * NCOND + n], a2);
            a2 = fmaf(pv2.w, Wa[(size_t)(hb + 11) * NCOND + n], a2);
            a3 = fmaf(pv3.x, Wa[(size_t)(hb + 12) * NCOND + n], a3);
            a3 = fmaf(pv3.y, Wa[(size_t)(hb + 13) * NCOND + n], a3);
            a3 = fmaf(pv3.z, Wa[(size_t)(hb + 14) * NCOND + n], a3);
            a3 = fmaf(pv3.w, Wa[(size_t)(hb + 15) * NCOND + n], a3);
        }
        {   // tail: h = 592..599
            const float4 pv0 = p4[148];
            const float4 pv1 = p4[149];
            a0 = fmaf(pv0.x, Wa[(size_t)592 * NCOND + n], a0);
            a0 = fmaf(pv0.y, Wa[(size_t)593 * NCOND + n], a0);
            a0 = fmaf(pv0.z, Wa[(size_t)594 * NCOND + n], a0);
            a0 = fmaf(pv0.w, Wa[(size_t)595 * NCOND + n], a0);
            a1 = fmaf(pv1.x, Wa[(size_t)596 * NCOND + n], a1);
            a1 = fmaf(pv1.y, Wa[(size_t)597 * NCOND + n], a1);
            a1 = fmaf(pv1.z, Wa[(size_t)598 * NCOND + n], a1);
            a1 = fmaf(pv1.w, Wa[(size_t)599 * NCOND + n], a1);
        }
        const float acc  = (a0 + a1) + (a2 + a3);
        const float gate = 1.0f / (1.0f + expf(-acc));
        out[(size_t)b * NCOND + n] = gate * x[(size_t)b * NCOND + n];
    }
}

extern "C" void kernel_launch(void* const* d_in, const int* in_sizes, int n_in,
                              void* d_out, int out_size, void* d_ws, size_t ws_size,
                              hipStream_t stream)
{
    // setup_inputs() order: x, context, lengths, W1, b1, Wa, ba
    const float* x       = (const float*)d_in[0];
    const float* ctx     = (const float*)d_in[1];
    const int*   lengths = (const int*)  d_in[2];
    const float* W1      = (const float*)d_in[3];
    const float* b1      = (const float*)d_in[4];
    const float* Wa      = (const float*)d_in[5];
    const float* ba      = (const float*)d_in[6];
    float*       out     = (float*)d_out;

    // ws layout: [w1t frag-major bf16: 409,600 B][partial fp32 8*256*600: 4,915,200 B]
    unsigned short* w1t     = (unsigned short*)d_ws;
    float*          partial = (float*)((char*)d_ws + 409600);

    k0_w1t<<<100, 256, 0, stream>>>(W1, w1t);
    k1_mfma_pool<<<dim3(BB, NSEG, 2), 256, 0, stream>>>(ctx, lengths, w1t, b1, partial);
    k2_gate<<<BB / 2, 640, 0, stream>>>(x, lengths, partial, Wa, ba, out);
}

// Round 2
// 309.516 us; speedup vs baseline: 1.1100x; 1.1100x over previous
//
#include <hip/hip_runtime.h>
#include <math.h>

// Problem constants: B=256, LMAX=512, NCOND=300, NHID=600
#define BB     256
#define LMAX   512
#define NCOND  300
#define NHID   600
#define NSEG   8          // 8 segments of 64 tokens; block = one segment chunk
#define CHUNK  64
#define KPAD   320        // K padded to 10 chunks of 32 (k>=300 REAL zeros in ctx16/W1T)
#define KLDS   328        // fallback-path LDS row stride
#define NKC    10         // KPAD/32

#define AS1 __attribute__((address_space(1)))
#define AS3 __attribute__((address_space(3)))

typedef short s16x8 __attribute__((ext_vector_type(8)));  // MFMA A/B frag (8 bf16)
typedef float f32x4 __attribute__((ext_vector_type(4)));  // MFMA accumulator
typedef unsigned short u16x4 __attribute__((ext_vector_type(4)));

// fp32 -> bf16 round-to-nearest-even
__device__ inline unsigned short f2bf(float f) {
    unsigned int x = __float_as_uint(f);
    x += 0x7fffu + ((x >> 16) & 1u);
    return (unsigned short)(x >> 16);
}

// ---------------------------------------------------------------------------
// k0: build W1T bf16 in FRAGMENT-MAJOR layout:
//   w1t[((ntile*NKC + kc)*64 + lane)*8 + j] = W1[kc*32+(lane>>4)*8+j][ntile*16+(lane&15)]
// -> a wave's B-frag load is one contiguous 1 KB global_load_dwordx4.
// ---------------------------------------------------------------------------
__global__ __launch_bounds__(256) void k0_w1t(const float* __restrict__ W1,
                                              unsigned short* __restrict__ w1t)
{
    const int t     = blockIdx.x * 256 + threadIdx.x;  // 0..25599
    const int lane  = t & 63;
    const int g     = t >> 6;                          // ntile*NKC + kc
    const int ntile = g / NKC;
    const int kc    = g - ntile * NKC;
    const int n     = ntile * 16 + (lane & 15);
    const int kbase = kc * 32 + (lane >> 4) * 8;
    union { unsigned short us[8]; s16x8 v8; } u;
#pragma unroll
    for (int j = 0; j < 8; ++j) {
        const int k = kbase + j;
        const float w = (n < NHID && k < NCOND) ? W1[(size_t)k * NHID + n] : 0.f;
        u.us[j] = f2bf(w);
    }
    *(s16x8*)(w1t + (size_t)t * 8) = u.v8;
}

// ---------------------------------------------------------------------------
// k0b: pre-convert ctx (fp32) -> ctx16 (bf16), live segments only.
//   Row layout: KPAD=320 elems/row; k in [300,320) written as REAL zeros
//   (so k1's kc=9 A-frags multiply 0*0 -- no NaN/garbage hazard anywhere).
//   Byte layout within a 40,960 B segment is PRE-SWIZZLED:
//     off' = (row*640 + kbyte) ^ ((row&7)<<4)
//   so that k1's LINEAR global_load_lds DMA lands the tile swizzled in LDS
//   (rule #21: inverse-swz source + linear DMA dest + swz on ds_read).
//   Per segment: 5120 8-byte output chunks / 256 threads = 20 iters, exact.
// ---------------------------------------------------------------------------
__global__ __launch_bounds__(256) void k0b_cvt(const float* __restrict__ ctx,
                                               const int* __restrict__ lengths,
                                               unsigned short* __restrict__ ctx16)
{
    const int b = blockIdx.x, s = blockIdx.y, tid = threadIdx.x;
    int count = lengths[b]; if (count < 1) count = 1;
    if (s * CHUNK >= count) return;                    // dead segment: k1 never reads it

    const size_t inbase  = ((size_t)b * LMAX + s * CHUNK) * NCOND;  // fp32 elems
    const float* src = ctx + inbase;
    char* dst = (char*)(ctx16 + ((size_t)b * LMAX + s * CHUNK) * KPAD);

#pragma unroll
    for (int i = 0; i < 20; ++i) {
        const int c   = i * 256 + tid;      // 0..5119 (8B output chunk index)
        const int row = c / 80;             // 0..63
        const int q   = c - row * 80;       // 0..79 (4-elem group; k = q*4)
        float4 v = make_float4(0.f, 0.f, 0.f, 0.f);
        if (q < 75)                         // k = q*4 <= 296; 16B load is aligned (row base 1200 B)
            v = *(const float4*)(src + (size_t)row * NCOND + q * 4);
        union { unsigned short us[4]; u16x4 v4; } o;
        o.us[0] = f2bf(v.x); o.us[1] = f2bf(v.y);
        o.us[2] = f2bf(v.z); o.us[3] = f2bf(v.w);
        const int off = (row * 640 + q * 8) ^ ((row & 7) << 4);   // swz bits 4-6; 8B align kept
        *(u16x4*)(dst + off) = o.v4;
    }
}

// ---------------------------------------------------------------------------
// k1 (fast path): grid (BB, NSEG, 2). Same decomposition as the proven v1
//   (wave owns 5 n-tiles x 4 m-tiles), but staging is 10 fire-and-forget
//   global_load_lds width-16 issues per wave (40,960 B exactly; no registers,
//   no VALU convert, no ds_write). kc=0 B-frags prefetched before the barrier.
//   A-frag ds_reads XOR the swizzle baked into ctx16 by k0b.
// ---------------------------------------------------------------------------
__global__ __launch_bounds__(256, 3) void k1_mfma_dma(
    const unsigned short* __restrict__ ctx16, const int* __restrict__ lengths,
    const unsigned short* __restrict__ w1t, const float* __restrict__ b1,
    float* __restrict__ partial)
{
    const int b  = blockIdx.x;
    const int s  = blockIdx.y;
    const int ch = blockIdx.z;

    int count = lengths[b]; if (count < 1) count = 1;
    const int l0 = s * CHUNK;
    if (l0 >= count) return;
    const int valid = min(count - l0, CHUNK);

    const int tid  = threadIdx.x;
    const int lane = tid & 63;
    const int wv   = tid >> 6;
    const int ln15 = lane & 15;
    const int kg   = lane >> 4;

    __shared__ __align__(16) unsigned short atile[CHUNK * KPAD];   // 40,960 B

    // ---- stage: 10 DMA issues per wave, linear copy of the pre-swizzled chunk
    const char* gsrc = (const char*)(ctx16 + ((size_t)b * LMAX + l0) * KPAD);
    char* lbase = (char*)atile;
#pragma unroll
    for (int r = 0; r < 10; ++r) {
        const int off = (r * 4 + wv) * 1024;       // wave-uniform LDS base; HW adds lane*16
        __builtin_amdgcn_global_load_lds(
            (const AS1 void*)(gsrc + off + lane * 16),
            (AS3 void*)(lbase + off),
            16, 0, 0);
    }

    // ---- prefetch kc=0 B-frags while the DMA drains (independent of LDS)
    const int ntile0 = ch * 20 + wv * 5;
    const unsigned short* bbase = w1t + ((size_t)ntile0 * NKC * 64 + lane) * 8;
    s16x8 bf[2][5];
#pragma unroll
    for (int nt = 0; nt < 5; ++nt) bf[0][nt] = *(const s16x8*)(bbase + nt * 5120);

    __syncthreads();

    // ---- MFMA: A-frag byte addr = (row*640 + kg*16 + kc*64 + mt*10240) ^ swz
    const int swz   = (ln15 & 7) << 4;
    const int abase = ln15 * 640 + kg * 16;
    const char* ab  = (const char*)atile;

    f32x4 acc[5][4];
#pragma unroll
    for (int nt = 0; nt < 5; ++nt)
#pragma unroll
        for (int mt = 0; mt < 4; ++mt) acc[nt][mt] = (f32x4){0.f, 0.f, 0.f, 0.f};

#pragma unroll
    for (int kc = 0; kc < NKC; ++kc) {
        const int cur = kc & 1, nxt = cur ^ 1;
        if (kc < NKC - 1) {
#pragma unroll
            for (int nt = 0; nt < 5; ++nt)
                bf[nxt][nt] = *(const s16x8*)(bbase + nt * 5120 + (kc + 1) * 512);
        }
        s16x8 af[4];
#pragma unroll
        for (int mt = 0; mt < 4; ++mt)
            af[mt] = *(const s16x8*)(ab + ((abase + mt * 10240 + kc * 64) ^ swz));
#pragma unroll
        for (int nt = 0; nt < 5; ++nt)
#pragma unroll
            for (int mt = 0; mt < 4; ++mt)
                acc[nt][mt] = __builtin_amdgcn_mfma_f32_16x16x32_bf16(
                    af[mt], bf[cur][nt], acc[nt][mt], 0, 0, 0);
    }

    // ---- epilogue: bias + ReLU, mask rows >= valid, reduce k-groups, write
#pragma unroll
    for (int nt = 0; nt < 5; ++nt) {
        const int colg = ch * 320 + wv * 80 + nt * 16 + ln15;
        const float b1c = (colg < NHID) ? b1[colg] : 0.f;
        float ssum = 0.f;
#pragma unroll
        for (int mt = 0; mt < 4; ++mt) {
            const int rbase = mt * 16 + kg * 4;
#pragma unroll
            for (int r = 0; r < 4; ++r) {
                const float h = fmaxf(acc[nt][mt][r] + b1c, 0.f);
                if (rbase + r < valid) ssum += h;
            }
        }
        ssum += __shfl_xor(ssum, 16, 64);
        ssum += __shfl_xor(ssum, 32, 64);
        if (kg == 0 && colg < NHID)
            partial[((size_t)s * BB + b) * NHID + colg] = ssum;
    }
}

// ---------------------------------------------------------------------------
// k1 (fallback, EXACT round-0 v1): used only if ws_size can't hold ctx16.
// ---------------------------------------------------------------------------
__global__ __launch_bounds__(256, 3) void k1_mfma_pool(
    const float* __restrict__ ctx, const int* __restrict__ lengths,
    const unsigned short* __restrict__ w1t, const float* __restrict__ b1,
    float* __restrict__ partial)
{
    const int b  = blockIdx.x;
    const int s  = blockIdx.y;
    const int ch = blockIdx.z;

    int count = lengths[b]; if (count < 1) count = 1;
    const int l0 = s * CHUNK;
    if (l0 >= count) return;
    const int valid = min(count - l0, CHUNK);

    const int tid  = threadIdx.x;
    const int lane = tid & 63;
    const int wv   = tid >> 6;
    const int ln15 = lane & 15;
    const int kg   = lane >> 4;

    __shared__ __align__(16) unsigned short atile[CHUNK * KLDS];   // 41,984 B

#pragma unroll
    for (int p = 0; p < 10; ++p) {
        const int i  = p * 256 + tid;
        const int r  = i / 40;
        const int c8 = i - r * 40;
        union { unsigned short us[8]; s16x8 v8; } u;
        if (r < valid && c8 < 38) {
            const float* src = ctx + ((size_t)b * LMAX + l0 + r) * NCOND + c8 * 8;
            const float4 v0 = *(const float4*)src;
            float4 v1 = make_float4(0.f, 0.f, 0.f, 0.f);
            if (c8 < 37) v1 = *(const float4*)(src + 4);
            u.us[0] = f2bf(v0.x); u.us[1] = f2bf(v0.y);
            u.us[2] = f2bf(v0.z); u.us[3] = f2bf(v0.w);
            u.us[4] = f2bf(v1.x); u.us[5] = f2bf(v1.y);
            u.us[6] = f2bf(v1.z); u.us[7] = f2bf(v1.w);
        } else {
#pragma unroll
            for (int j = 0; j < 8; ++j) u.us[j] = 0;
        }
        *(s16x8*)(atile + r * KLDS + c8 * 8) = u.v8;
    }
    __syncthreads();

    const int ntile0 = ch * 20 + wv * 5;
    const unsigned short* bbase = w1t + ((size_t)ntile0 * NKC * 64 + lane) * 8;
    const unsigned short* arow  = atile + ln15 * KLDS + kg * 8;

    f32x4 acc[5][4];
#pragma unroll
    for (int nt = 0; nt < 5; ++nt)
#pragma unroll
        for (int mt = 0; mt < 4; ++mt) acc[nt][mt] = (f32x4){0.f, 0.f, 0.f, 0.f};

    s16x8 bf[2][5];
#pragma unroll
    for (int nt = 0; nt < 5; ++nt) bf[0][nt] = *(const s16x8*)(bbase + nt * 5120);

#pragma unroll
    for (int kc = 0; kc < NKC; ++kc) {
        const int cur = kc & 1, nxt = cur ^ 1;
        if (kc < NKC - 1) {
#pragma unroll
            for (int nt = 0; nt < 5; ++nt)
                bf[nxt][nt] = *(const s16x8*)(bbase + nt * 5120 + (kc + 1) * 512);
        }
        s16x8 af[4];
#pragma unroll
        for (int mt = 0; mt < 4; ++mt)
            af[mt] = *(const s16x8*)(arow + mt * 16 * KLDS + kc * 32);
#pragma unroll
        for (int nt = 0; nt < 5; ++nt)
#pragma unroll
            for (int mt = 0; mt < 4; ++mt)
                acc[nt][mt] = __builtin_amdgcn_mfma_f32_16x16x32_bf16(
                    af[mt], bf[cur][nt], acc[nt][mt], 0, 0, 0);
    }

#pragma unroll
    for (int nt = 0; nt < 5; ++nt) {
        const int colg = ch * 320 + wv * 80 + nt * 16 + ln15;
        const float b1c = (colg < NHID) ? b1[colg] : 0.f;
        float ssum = 0.f;
#pragma unroll
        for (int mt = 0; mt < 4; ++mt) {
            const int rbase = mt * 16 + kg * 4;
#pragma unroll
            for (int r = 0; r < 4; ++r) {
                const float h = fmaxf(acc[nt][mt][r] + b1c, 0.f);
                if (rbase + r < valid) ssum += h;
            }
        }
        ssum += __shfl_xor(ssum, 16, 64);
        ssum += __shfl_xor(ssum, 32, 64);
        if (kg == 0 && colg < NHID)
            partial[((size_t)s * BB + b) * NHID + colg] = ssum;
    }
}

// ---------------------------------------------------------------------------
// k2: 2 batches per block (same-n lanes share Wa loads). Reduce partials over
//     sp < ceil(len/64) (others unwritten/poisoned -> skipped), /len, then
//     gate = sigmoid(pooled@Wa + ba); out = gate * x.
// NOTE: NHID/4 = 150 float4s = 37*4 + 2 -> 4-wide main loop to h4<148, then
//       a 2-float4 tail. (Round 4 bug: stepping 4 to 150 overran pl AND Wa.)
// ---------------------------------------------------------------------------
__global__ __launch_bounds__(640) void k2_gate(
    const float* __restrict__ x, const int* __restrict__ lengths,
    const float* __restrict__ partial, const float* __restrict__ Wa,
    const float* __restrict__ ba, float* __restrict__ out)
{
    const int b0  = blockIdx.x * 2;
    const int tid = threadIdx.x;

    __shared__ float pl[2][NHID];

    if (tid < NHID) {
#pragma unroll
        for (int bb = 0; bb < 2; ++bb) {
            int count = lengths[b0 + bb]; if (count < 1) count = 1;
            const int nch = (count + CHUNK - 1) >> 6;
            float ssum = 0.f;
            for (int sp = 0; sp < nch; ++sp)
                ssum += partial[((size_t)sp * BB + (b0 + bb)) * NHID + tid];
            pl[bb][tid] = ssum / (float)count;
        }
    }
    __syncthreads();

    if (tid < 2 * NCOND) {
        const int bb = tid / NCOND;        // 0 or 1
        const int n  = tid - bb * NCOND;   // lanes 0..299 and 300..599 share Wa addrs
        const int b  = b0 + bb;
        float a0 = ba[n], a1 = 0.f, a2 = 0.f, a3 = 0.f;
        const float4* p4 = (const float4*)pl[bb];
        for (int h4 = 0; h4 < 148; h4 += 4) {   // h = 0..591
            const float4 pv0 = p4[h4];
            const float4 pv1 = p4[h4 + 1];
            const float4 pv2 = p4[h4 + 2];
            const float4 pv3 = p4[h4 + 3];
            const int hb = h4 * 4;
            a0 = fmaf(pv0.x, Wa[(size_t)(hb +  0) * NCOND + n], a0);
            a0 = fmaf(pv0.y, Wa[(size_t)(hb +  1) * NCOND + n], a0);
            a0 = fmaf(pv0.z, Wa[(size_t)(hb +  2) * NCOND + n], a0);
            a0 = fmaf(pv0.w, Wa[(size_t)(hb +  3) * NCOND + n], a0);
            a1 = fmaf(pv1.x, Wa[(size_t)(hb +  4) * NCOND + n], a1);
            a1 = fmaf(pv1.y, Wa[(size_t)(hb +  5) * NCOND + n], a1);
            a1 = fmaf(pv1.z, Wa[(size_t)(hb +  6) * NCOND + n], a1);
            a1 = fmaf(pv1.w, Wa[(size_t)(hb +  7) * NCOND + n], a1);
            a2 = fmaf(pv2.x, Wa[(size_t)(hb +  8) * NCOND + n], a2);
            a2 = fmaf(pv2.y, Wa[(size_t)(hb +  9) * NCOND + n], a2);
            a2 = fmaf(pv2.z, Wa[(size_t)(hb + 10) * NCOND + n], a2);
            a2 = fmaf(pv2.w, Wa[(size_t)(hb + 11) * NCOND + n], a2);
            a3 = fmaf(pv3.x, Wa[(size_t)(hb + 12) * NCOND + n], a3);
            a3 = fmaf(pv3.y, Wa[(size_t)(hb + 13) * NCOND + n], a3);
            a3 = fmaf(pv3.z, Wa[(size_t)(hb + 14) * NCOND + n], a3);
            a3 = fmaf(pv3.w, Wa[(size_t)(hb + 15) * NCOND + n], a3);
        }
        {   // tail: h = 592..599
            const float4 pv0 = p4[148];
            const float4 pv1 = p4[149];
            a0 = fmaf(pv0.x, Wa[(size_t)592 * NCOND + n], a0);
            a0 = fmaf(pv0.y, Wa[(size_t)593 * NCOND + n], a0);
            a0 = fmaf(pv0.z, Wa[(size_t)594 * NCOND + n], a0);
            a0 = fmaf(pv0.w, Wa[(size_t)595 * NCOND + n], a0);
            a1 = fmaf(pv1.x, Wa[(size_t)596 * NCOND + n], a1);
            a1 = fmaf(pv1.y, Wa[(size_t)597 * NCOND + n], a1);
            a1 = fmaf(pv1.z, Wa[(size_t)598 * NCOND + n], a1);
            a1 = fmaf(pv1.w, Wa[(size_t)599 * NCOND + n], a1);
        }
        const float acc  = (a0 + a1) + (a2 + a3);
        const float gate = 1.0f / (1.0f + expf(-acc));
        out[(size_t)b * NCOND + n] = gate * x[(size_t)b * NCOND + n];
    }
}

extern "C" void kernel_launch(void* const* d_in, const int* in_sizes, int n_in,
                              void* d_out, int out_size, void* d_ws, size_t ws_size,
                              hipStream_t stream)
{
    // setup_inputs() order: x, context, lengths, W1, b1, Wa, ba
    const float* x       = (const float*)d_in[0];
    const float* ctx     = (const float*)d_in[1];
    const int*   lengths = (const int*)  d_in[2];
    const float* W1      = (const float*)d_in[3];
    const float* b1      = (const float*)d_in[4];
    const float* Wa      = (const float*)d_in[5];
    const float* ba      = (const float*)d_in[6];
    float*       out     = (float*)d_out;

    // ws layout: [w1t 409,600 B][partial 4,915,200 B][ctx16 bf16 83,886,080 B]
    const size_t W1T_B   = 409600;
    const size_t PART_B  = 4915200;
    const size_t CTX16_B = (size_t)BB * LMAX * KPAD * 2;   // 83,886,080
    const size_t NEED    = W1T_B + PART_B + CTX16_B;        // 89,210,880

    unsigned short* w1t     = (unsigned short*)d_ws;
    float*          partial = (float*)((char*)d_ws + W1T_B);

    k0_w1t<<<100, 256, 0, stream>>>(W1, w1t);

    if (ws_size >= NEED) {
        unsigned short* ctx16 = (unsigned short*)((char*)d_ws + W1T_B + PART_B);
        k0b_cvt<<<dim3(BB, NSEG), 256, 0, stream>>>(ctx, lengths, ctx16);
        k1_mfma_dma<<<dim3(BB, NSEG, 2), 256, 0, stream>>>(ctx16, lengths, w1t, b1, partial);
    } else {
        // workspace too small for ctx16: exact round-0 path
        k1_mfma_pool<<<dim3(BB, NSEG, 2), 256, 0, stream>>>(ctx, lengths, w1t, b1, partial);
    }

    k2_gate<<<BB / 2, 640, 0, stream>>>(x, lengths, partial, Wa, ba, out);
}